// Round 5
// baseline (790.173 us; speedup 1.0000x reference)
//
#include <hip/hip_runtime.h>
#include <stdint.h>

// ---------- types ----------
typedef __attribute__((ext_vector_type(8)))  __bf16 bf16x8;   // MFMA A/B frag (4 VGPRs)
typedef __attribute__((ext_vector_type(16))) float  f32x16;   // 32x32 MFMA C/D frag
typedef unsigned short u16;
typedef __attribute__((ext_vector_type(8))) unsigned short u16x8;

#define GLOBAL_AS __attribute__((address_space(1)))
#define LDS_AS    __attribute__((address_space(3)))

__device__ __forceinline__ void load_lds16(const void* g, void* l) {
    __builtin_amdgcn_global_load_lds((const GLOBAL_AS void*)g, (LDS_AS void*)l, 16, 0, 0);
}

__device__ __forceinline__ u16 f2bf(float f) {
    union { float f; uint32_t u; } v; v.f = f;
    uint32_t r = v.u + 0x7FFFu + ((v.u >> 16) & 1u);   // RNE
    return (u16)(r >> 16);
}
__device__ __forceinline__ float b2f(u16 b) {
    union { uint32_t u; float f; } v; v.u = ((uint32_t)b) << 16;
    return v.f;
}

// ---------- aux: fp32 -> bf16 convert with zero-padding ----------
__global__ void k_conv_pad(const float* __restrict__ in, u16* __restrict__ out,
                           int rIn, int cIn, int cOut, int total8) {
    int idx = blockIdx.x * blockDim.x + threadIdx.x;
    if (idx >= total8) return;
    int c8n = cOut >> 3;
    int r  = idx / c8n;
    int c0 = (idx - r * c8n) << 3;
    u16x8 o;
#pragma unroll
    for (int j = 0; j < 8; ++j) {
        int c = c0 + j;
        o[j] = (r < rIn && c < cIn) ? f2bf(in[(size_t)r * cIn + c]) : (u16)0;
    }
    *(u16x8*)(out + (size_t)r * cOut + c0) = o;
}

// ---------- aux: fp32 [kIn x nIn] -> bf16 transposed [nOut x kOut], zero-padded ----------
__global__ void k_transpose_conv(const float* __restrict__ in, u16* __restrict__ out,
                                 int kIn, int nIn, int kOut) {
    __shared__ float tile[32][33];
    int k0 = blockIdx.x * 32, n0 = blockIdx.y * 32;
    int tx = threadIdx.x, ty = threadIdx.y;   // block (32,8)
#pragma unroll
    for (int i = 0; i < 4; ++i) {
        int k = k0 + ty + i * 8, n = n0 + tx;
        tile[ty + i * 8][tx] = (k < kIn && n < nIn) ? in[(size_t)k * nIn + n] : 0.f;
    }
    __syncthreads();
#pragma unroll
    for (int i = 0; i < 4; ++i) {
        int n = n0 + ty + i * 8, k = k0 + tx;
        out[(size_t)n * kOut + k] = f2bf(tile[tx][ty + i * 8]);
    }
}

// ---------- 256x128 GEMM v5: triple-buffer + COUNTED vmcnt (T4), 1 barrier/K-tile ----------
// R4 post-mortem: SQ_LDS_BANK_CONFLICT = 4 cyc/b128-read is invariant across every
// layout/swizzle tried (and m97 showed the same level at 874 TF) -> intrinsic b128
// service cost, not the lever. The lever never actually landed is T4: every round so
// far drains vmcnt(0) at every barrier (counted-vs-drain0 = +38-73%, m218).
// Structure: tile 256x128, 4 waves (2x2, per-wave 128x64), BK=32, THREE LDS buffers
// (72 KiB -> still 2 blocks/CU). Iter t: stage tile t+2 into cb2 (6 global_load_lds),
// read cb0 (12 ds_read_b128), 16 MFMA, then lgkmcnt(0) + vmcnt(6) + barrier.
// vmcnt(6) leaves only t+2's stage in flight => t+1 landed, with a full-iter
// (~2000 cyc > 900 cyc HBM) issue-to-wait lead. Never drains to 0 mid-loop.
// Ledger: reads of buf[t] follow iter-(t-1)'s barrier, which follows every wave's
// vmcnt(6) (t landed) and lgkmcnt(0) (reads of buf[t-1 mod 3] drained before its
// restage as t+2). Tail: vmcnt(0) at t=nT-2; no sync after t=nT-1.
// Staging/swizzle/fragment math identical to R4 (harness-verified): 64B rows,
// chunk pre-swizzle c^=(row>>1)&3 on source, same XOR on read; accumulation order
// per acc unchanged -> bit-identical numerics.

#define BARRIER() do { asm volatile("" ::: "memory"); \
                       __builtin_amdgcn_s_barrier(); \
                       asm volatile("" ::: "memory"); } while (0)
#define LGKM0()   do { asm volatile("s_waitcnt lgkmcnt(0)" ::: "memory"); \
                       __builtin_amdgcn_sched_barrier(0); } while (0)
#define VMCNT(n)  do { asm volatile("s_waitcnt vmcnt(" #n ")" ::: "memory"); \
                       __builtin_amdgcn_sched_barrier(0); } while (0)

// 6 global_load_lds: 4 A-sweeps (64 rows) + 2 B-sweeps for K-tile at elem offset koff
#define STAGE6(bb, koff) do { \
    _Pragma("unroll") for (int t_ = 0; t_ < 4; ++t_) \
        load_lds16(aS + (koff) + (size_t)(t_ * 64) * K, (bb) + t_ * 4096 + wOff); \
    _Pragma("unroll") for (int t_ = 0; t_ < 2; ++t_) \
        load_lds16(bS + (koff) + (size_t)(t_ * 64) * K, (bb) + 16384 + t_ * 4096 + wOff); \
} while (0)

// 6 frag reads for k-slice p (chunk byte = ch0 ^ (p<<5))
#define RD6(bb, p, FA, FB) do { \
    const int co_ = ch0 ^ ((p) << 5); \
    FA[0] = *(const bf16x8*)((bb) + aR +    0 + co_); \
    FA[1] = *(const bf16x8*)((bb) + aR + 2048 + co_); \
    FA[2] = *(const bf16x8*)((bb) + aR + 4096 + co_); \
    FA[3] = *(const bf16x8*)((bb) + aR + 6144 + co_); \
    FB[0] = *(const bf16x8*)((bb) + bR +    0 + co_); \
    FB[1] = *(const bf16x8*)((bb) + bR + 2048 + co_); \
} while (0)

#define MM8(FA, FB) do { \
    __builtin_amdgcn_s_setprio(1); \
    acc[0][0] = __builtin_amdgcn_mfma_f32_32x32x16_bf16(FA[0], FB[0], acc[0][0], 0, 0, 0); \
    acc[1][0] = __builtin_amdgcn_mfma_f32_32x32x16_bf16(FA[1], FB[0], acc[1][0], 0, 0, 0); \
    acc[2][0] = __builtin_amdgcn_mfma_f32_32x32x16_bf16(FA[2], FB[0], acc[2][0], 0, 0, 0); \
    acc[3][0] = __builtin_amdgcn_mfma_f32_32x32x16_bf16(FA[3], FB[0], acc[3][0], 0, 0, 0); \
    acc[0][1] = __builtin_amdgcn_mfma_f32_32x32x16_bf16(FA[0], FB[1], acc[0][1], 0, 0, 0); \
    acc[1][1] = __builtin_amdgcn_mfma_f32_32x32x16_bf16(FA[1], FB[1], acc[1][1], 0, 0, 0); \
    acc[2][1] = __builtin_amdgcn_mfma_f32_32x32x16_bf16(FA[2], FB[1], acc[2][1], 0, 0, 0); \
    acc[3][1] = __builtin_amdgcn_mfma_f32_32x32x16_bf16(FA[3], FB[1], acc[3][1], 0, 0, 0); \
    __builtin_amdgcn_s_setprio(0); \
} while (0)

template <int MODE>
__global__ __launch_bounds__(256, 2) void k_gemm128(
    const u16* __restrict__ A, const u16* __restrict__ B,
    const u16* __restrict__ bias, void* __restrict__ Cv,
    int K, int ldc, int mReal, int nReal, int gx) {
    __shared__ __align__(16) char lds[73728];   // 3 x 24 KiB buffers

    const int tid  = threadIdx.x;
    const int w    = tid >> 6, lane = tid & 63;
    const int l31  = lane & 31, hi = lane >> 5;
    const int wr   = w & 1, wc = w >> 1;            // 2x2 wave grid, per-wave 128x64

    // bijective XCD-chunked swizzle (m204 form; works for any grid size)
    const int nwg = (int)gridDim.x;
    const int q   = nwg >> 3, r = nwg & 7;
    const int xcd = (int)blockIdx.x & 7, lid = (int)blockIdx.x >> 3;
    const int wg  = (xcd < r ? xcd * (q + 1) : r * (q + 1) + (xcd - r) * q) + lid;
    const int bm  = (wg / gx) * 256;
    const int bn  = (wg % gx) * 128;

    // rotating buffers: cb0 = read (tile t), cb2 = stage target (tile t+2)
    char* cb0 = lds;
    char* cb1 = lds + 24576;
    char* cb2 = lds + 49152;

    // staging: coalesced source rows, pre-swizzled chunk (c ^= (row>>1)&3)
    const int srcRow = tid >> 2;                     // 0..63 (+64t per sweep)
    const int srcCh  = (tid & 3) ^ ((srcRow >> 1) & 3);
    const int wOff   = (tid & ~63) << 4;             // wave slot (1 KiB per wave/sweep)

    // ds_read bases; k-slice p chunk byte = ch0 ^ (p<<5)
    const int aR  = (wr * 128 + l31) * 64;
    const int bR  = 16384 + (wc * 64 + l31) * 64;
    const int ch0 = ((hi ^ ((l31 >> 1) & 3))) << 4;

    const u16* const aS = A + (size_t)(bm + srcRow) * K + (srcCh << 3);
    const u16* const bS = B + (size_t)(bn + srcRow) * K + (srcCh << 3);

    f32x16 acc[4][2];
#pragma unroll
    for (int i = 0; i < 4; ++i)
#pragma unroll
        for (int j = 0; j < 2; ++j) acc[i][j] = (f32x16)(0.f);

    bf16x8 xa[4], xb[2], ya[4], yb[2];

    const int nT = K >> 5;             // 32-K tiles (all K are multiples of 32; nT >= 2)

    // prologue: tiles 0,1 in flight; wait tile 0 only (counted)
    STAGE6(cb0, 0);
    STAGE6(cb1, 32);
    VMCNT(6);
    BARRIER();

#pragma unroll 1
    for (int t = 0; t < nT; ++t) {
        if (t + 2 < nT) { STAGE6(cb2, (size_t)(t + 2) * 32); }
        RD6(cb0, 0, xa, xb);
        RD6(cb0, 1, ya, yb);
        MM8(xa, xb);
        MM8(ya, yb);
        if (t + 1 < nT) {
            LGKM0();                   // this wave's cb0 reads drained (WAR for restage)
            if (t + 2 < nT) { VMCNT(6); }   // tile t+1 landed; t+2 stays in flight
            else           { VMCNT(0); }    // drain: next tile is the last
            BARRIER();
        }
        char* tp = cb0; cb0 = cb1; cb1 = cb2; cb2 = tp;
    }

    // epilogue. 32x32 C/D layout: col = lane&31, row = (reg&3) + 8*(reg>>2) + 4*hi
    float bv[2];
    if (MODE >= 1) {
#pragma unroll
        for (int ni = 0; ni < 2; ++ni) bv[ni] = b2f(bias[bn + wc * 64 + ni * 32 + l31]);
    }
#pragma unroll
    for (int mi = 0; mi < 4; ++mi) {
#pragma unroll
        for (int reg = 0; reg < 16; ++reg) {
            const int row = bm + wr * 128 + mi * 32 + (reg & 3) + 8 * (reg >> 2) + 4 * hi;
#pragma unroll
            for (int ni = 0; ni < 2; ++ni) {
                const int col = bn + wc * 64 + ni * 32 + l31;
                float vv = acc[mi][ni][reg];
                if (MODE == 0) {
                    if (row < mReal && col < nReal)
                        ((u16*)Cv)[(size_t)row * ldc + col] = f2bf(vv);
                } else if (MODE == 1) {
                    vv += bv[ni];
                    vv = vv > 0.f ? vv : 0.f;
                    ((u16*)Cv)[(size_t)row * ldc + col] = f2bf(vv);
                } else {
                    ((float*)Cv)[(size_t)row * ldc + col] = vv + bv[ni];
                }
            }
        }
    }
}

// ---------- launch ----------
// Sizes: D_IN=2048, D_H=4096, D_OUT=2048, B=4096; SIZE_N=5794, SIZE_M=2897
// Padded GEMM0 dims: M=N=5888 (23*256 / 46*128), K=2944
// Vf flat unpack offsets (elems):
//   W1 @ 0, b1 @ 8388608, W2 @ 8392704, b2 @ 25169920, W3 @ 25174016, b3 @ 33562624
extern "C" void kernel_launch(void* const* d_in, const int* in_sizes, int n_in,
                              void* d_out, int out_size, void* d_ws, size_t ws_size,
                              hipStream_t stream) {
    (void)in_sizes; (void)n_in; (void)out_size; (void)ws_size;
    const float* x  = (const float*)d_in[0];
    const float* V1 = (const float*)d_in[1];
    const float* V2 = (const float*)d_in[2];

    char* ws = (char*)d_ws;
    u16* Vf   = (u16*)(ws);                            // 5794*5794 bf16 -> 67,140,872 B
    u16* V1b  = (u16*)(ws + 67141120);                 // [5888 x 2944] bf16 = 34,668,544 B
    u16* V2bT = (u16*)(ws + 67141120 + 34668544);      // [5888 x 2944] bf16
    u16* Xb   = (u16*)(ws + 67141120 + 2 * 34668544);  // [4096 x 2048] bf16
    u16* H1   = V1b;   // dead after GEMM0
    u16* H2   = V2bT;

    k_conv_pad<<<8464, 256, 0, stream>>>(V1, V1b, 5794, 2897, 2944, 5888 * 2944 / 8);
    k_transpose_conv<<<dim3(92, 184), dim3(32, 8), 0, stream>>>(V2, V2bT, 2897, 5794, 2944);
    k_conv_pad<<<4096, 256, 0, stream>>>(x, Xb, 4096, 2048, 2048, 4096 * 2048 / 8);

    // G0: Vf = V1 @ V2  (padded 5888x5888x2944; 23x46 = 1058 tiles, 2 blocks/CU)
    k_gemm128<0><<<1058, 256, 0, stream>>>(V1b, V2bT, nullptr, Vf,
                                           2944, 5794, 5794, 5794, 46);
    // G1: H1 = relu(Xb @ W1^T + b1)   [4096x4096], K=2048 (16x32 = 512 = all-resident)
    k_gemm128<1><<<512, 256, 0, stream>>>(Xb, Vf + 0, Vf + 8388608, H1,
                                          2048, 4096, 4096, 4096, 32);
    // G2: H2 = relu(H1 @ W2^T + b2)   [4096x4096], K=4096
    k_gemm128<1><<<512, 256, 0, stream>>>(H1, Vf + 8392704, Vf + 25169920, H2,
                                          4096, 4096, 4096, 4096, 32);
    // G3: out = H2 @ W3^T + b3        [4096x2048] fp32, K=4096 (16x16 = 256 tiles)
    k_gemm128<2><<<256, 256, 0, stream>>>(H2, Vf + 25174016, Vf + 33562624, d_out,
                                          4096, 2048, 4096, 2048, 16);
}

// Round 7
// 700.493 us; speedup vs baseline: 1.1280x; 1.1280x over previous
//
#include <hip/hip_runtime.h>
#include <stdint.h>

// ---------- types ----------
typedef __attribute__((ext_vector_type(8)))  __bf16 bf16x8;   // MFMA A/B frag (4 VGPRs)
typedef __attribute__((ext_vector_type(4)))  float  f32x4;    // 16x16 MFMA C/D frag
typedef __attribute__((ext_vector_type(16))) float  f32x16;   // 32x32 MFMA C/D frag
typedef unsigned short u16;
typedef __attribute__((ext_vector_type(8))) unsigned short u16x8;

#define GLOBAL_AS __attribute__((address_space(1)))
#define LDS_AS    __attribute__((address_space(3)))

__device__ __forceinline__ void load_lds16(const void* g, void* l) {
    __builtin_amdgcn_global_load_lds((const GLOBAL_AS void*)g, (LDS_AS void*)l, 16, 0, 0);
}

__device__ __forceinline__ u16 f2bf(float f) {
    union { float f; uint32_t u; } v; v.f = f;
    uint32_t r = v.u + 0x7FFFu + ((v.u >> 16) & 1u);   // RNE
    return (u16)(r >> 16);
}
__device__ __forceinline__ float b2f(u16 b) {
    union { uint32_t u; float f; } v; v.u = ((uint32_t)b) << 16;
    return v.f;
}

// ---------- aux: fp32 -> bf16 convert with zero-padding ----------
__global__ void k_conv_pad(const float* __restrict__ in, u16* __restrict__ out,
                           int rIn, int cIn, int cOut, int total8) {
    int idx = blockIdx.x * blockDim.x + threadIdx.x;
    if (idx >= total8) return;
    int c8n = cOut >> 3;
    int r  = idx / c8n;
    int c0 = (idx - r * c8n) << 3;
    u16x8 o;
#pragma unroll
    for (int j = 0; j < 8; ++j) {
        int c = c0 + j;
        o[j] = (r < rIn && c < cIn) ? f2bf(in[(size_t)r * cIn + c]) : (u16)0;
    }
    *(u16x8*)(out + (size_t)r * cOut + c0) = o;
}

// ---------- aux: fp32 [kIn x nIn] -> bf16 transposed [nOut x kOut], zero-padded ----------
__global__ void k_transpose_conv(const float* __restrict__ in, u16* __restrict__ out,
                                 int kIn, int nIn, int kOut) {
    __shared__ float tile[32][33];
    int k0 = blockIdx.x * 32, n0 = blockIdx.y * 32;
    int tx = threadIdx.x, ty = threadIdx.y;   // block (32,8)
#pragma unroll
    for (int i = 0; i < 4; ++i) {
        int k = k0 + ty + i * 8, n = n0 + tx;
        tile[ty + i * 8][tx] = (k < kIn && n < nIn) ? in[(size_t)k * nIn + n] : 0.f;
    }
    __syncthreads();
#pragma unroll
    for (int i = 0; i < 4; ++i) {
        int n = n0 + ty + i * 8, k = k0 + tx;
        out[(size_t)n * kOut + k] = f2bf(tile[tx][ty + i * 8]);
    }
}

// ---------- old 128x128 kernel (kept for G3: proven ~97us at 4 blocks/CU) ----------
template <int MODE>
__global__ __launch_bounds__(256, 4) void k_gemm_bt(
    const u16* __restrict__ A, const u16* __restrict__ B,
    const u16* __restrict__ bias, void* __restrict__ Cv,
    int K, int ldc, int mReal, int nReal) {
    (void)bias;
    __shared__ __align__(16) char lds[32768];
    char* As = lds;
    char* Bs = lds + 16384;

    const int tid  = threadIdx.x;
    const int w    = tid >> 6, lane = tid & 63;
    const int l31  = lane & 31, hi = lane >> 5;
    const int wm   = (w & 1) * 64, wn = (w >> 1) * 64;
    const int bm   = blockIdx.y * 128, bn = blockIdx.x * 128;

    const int srcRow = tid >> 3;
    const int srcCol = (tid & 7) ^ (srcRow & 7);
    const u16* aSrc = A + (size_t)(bm + srcRow) * K + (srcCol << 3);
    const u16* bSrc = B + (size_t)(bn + srcRow) * K + (srcCol << 3);
    char* aDst = As + ((tid & ~63) << 4);
    char* bDst = Bs + ((tid & ~63) << 4);

    const int aRow0 = (wm + l31) * 128;
    const int aRow1 = (wm + 32 + l31) * 128;
    const int bRow0 = (wn + l31) * 128;
    const int bRow1 = (wn + 32 + l31) * 128;

    f32x16 acc[2][2];
#pragma unroll
    for (int i = 0; i < 2; ++i)
#pragma unroll
        for (int j = 0; j < 2; ++j) acc[i][j] = (f32x16)(0.f);

    for (int k0 = 0; k0 < K; k0 += 64) {
#pragma unroll
        for (int t = 0; t < 4; ++t) {
            load_lds16(aSrc + (size_t)(t * 32) * K, aDst + t * 4096);
            load_lds16(bSrc + (size_t)(t * 32) * K, bDst + t * 4096);
        }
        aSrc += 64; bSrc += 64;
        __syncthreads();
#pragma unroll
        for (int ks = 0; ks < 4; ++ks) {
            const int swz = (((ks * 2 + hi) ^ (l31 & 7)) << 4);
            bf16x8 af[2], bfr[2];
            af[0]  = *(const bf16x8*)(As + aRow0 + swz);
            af[1]  = *(const bf16x8*)(As + aRow1 + swz);
            bfr[0] = *(const bf16x8*)(Bs + bRow0 + swz);
            bfr[1] = *(const bf16x8*)(Bs + bRow1 + swz);
#pragma unroll
            for (int mi = 0; mi < 2; ++mi)
#pragma unroll
                for (int ni = 0; ni < 2; ++ni)
                    acc[mi][ni] = __builtin_amdgcn_mfma_f32_32x32x16_bf16(
                        af[mi], bfr[ni], acc[mi][ni], 0, 0, 0);
        }
        __syncthreads();
    }

    float bv[2];
    if (MODE >= 1) {
#pragma unroll
        for (int ni = 0; ni < 2; ++ni) bv[ni] = b2f(bias[bn + wn + ni * 32 + l31]);
    }
#pragma unroll
    for (int mi = 0; mi < 2; ++mi) {
#pragma unroll
        for (int reg = 0; reg < 16; ++reg) {
            int row = bm + wm + mi * 32 + (reg & 3) + 8 * (reg >> 2) + 4 * hi;
#pragma unroll
            for (int ni = 0; ni < 2; ++ni) {
                int col = bn + wn + ni * 32 + l31;
                float v = acc[mi][ni][reg];
                if (MODE == 0) {
                    if (row < mReal && col < nReal)
                        ((u16*)Cv)[(size_t)row * ldc + col] = f2bf(v);
                } else if (MODE == 1) {
                    v += bv[ni];
                    v = v > 0.f ? v : 0.f;
                    ((u16*)Cv)[(size_t)row * ldc + col] = f2bf(v);
                } else {
                    ((float*)Cv)[(size_t)row * ldc + col] = v + bv[ni];
                }
            }
        }
    }
}

// ---------- 256x256 8-phase GEMM, R7: CORRECTED stage ledger ----------
// R6 failed: half-selection is BY WAVE (wr picks A-half, wc>>1 picks B-half), so
// ph1 reads rows 0-63 of BOTH A-halves and ph3 rows 64-127 of both; staging
// buf0.A0 at ph2 (R6's S2) clobbered rows read at ph3. Corrected read-set ledger:
//   buf0.A read ph1+ph3 (free ph4) | buf0.B read ph1+ph2 (free ph3)
//   buf1.A read ph5+ph7 (free ph8) | buf1.B read ph5+ph6 (free ph7)
// Stage slots (1 half = 2 global_load_lds per phase; iter J reads 2J,2J+1):
//   ph1: buf1.A0<-2J+1  ph2: buf1.A1<-2J+1  (WAR ok: buf1.A free since prev ph8)
//   ph3: buf0.B0<-2J+2  ph4: buf0.B1        (buf0.B free at ph3)
//   ph5: buf0.A0<-2J+2  ph6: buf0.A1        (buf0.A free at ph4)
//   ph7: buf1.B0<-2J+3  ph8: buf1.B1        (buf1.B free at ph7)
// Counted vmcnt, never 0 mid-loop:
//   ph4: VMCNT(4) keeps {ph3,ph4}; drains prev ph7/8 (buf1.B) + ph1/2 (buf1.A)
//        => buf1 complete before ph5 reads.
//   ph8: VMCNT(4) keeps {ph7,ph8}; drains ph3-6 (buf0) => complete before next ph1.
// Prologue: buf0 full (8 loads) + buf1.B (4 loads), VMCNT(4). Last iter: skip
// ph3-8 stages, VMCNT(0) at ph4 (drains ph1/2's buf1.A). Epilogue stores are
// older than any later vmcnt wait -> drained naturally (correct, persistent loop).

#define BARRIER() do { asm volatile("" ::: "memory"); \
                       __builtin_amdgcn_s_barrier(); \
                       asm volatile("" ::: "memory"); } while (0)
#define LGKM0()   do { asm volatile("s_waitcnt lgkmcnt(0)" ::: "memory"); \
                       __builtin_amdgcn_sched_barrier(0); } while (0)
#define LGKM8()   do { asm volatile("s_waitcnt lgkmcnt(8)" ::: "memory"); \
                       __builtin_amdgcn_sched_barrier(0); } while (0)
#define VMCNT(n)  do { asm volatile("s_waitcnt vmcnt(" #n ")" ::: "memory"); \
                       __builtin_amdgcn_sched_barrier(0); } while (0)

// stage one A-half / B-half (2 x global_load_lds, sweeps of 64 rows each)
#define STG_A(BUFB, H, KT) do { \
    load_lds16(aStage + (size_t)((H) * 128)      * K + (KT), lds + (BUFB) * 65536 + (H) * 16384 +        ldsW); \
    load_lds16(aStage + (size_t)((H) * 128 + 64) * K + (KT), lds + (BUFB) * 65536 + (H) * 16384 + 8192 + ldsW); \
} while (0)
#define STG_B(BUFB, H, KT) do { \
    load_lds16(bStage + (size_t)((H) * 128)      * K + (KT), lds + (BUFB) * 65536 + 32768 + (H) * 16384 +        ldsW); \
    load_lds16(bStage + (size_t)((H) * 128 + 64) * K + (KT), lds + (BUFB) * 65536 + 32768 + (H) * 16384 + 8192 + ldsW); \
} while (0)

// frag reads: A quadrant MH (4 frags x 2 ksteps = 8), B quadrant NH (2 x 2 = 4)
#define RDA(BUFB, MH) do { \
    _Pragma("unroll") for (int m2 = 0; m2 < 4; ++m2) { \
        a[m2][0] = *(const bf16x8*)(lds + (BUFB) * 65536 + aWave + (MH) * 8192 + m2 * 2048 + laneF); \
        a[m2][1] = *(const bf16x8*)(lds + (BUFB) * 65536 + aWave + (MH) * 8192 + m2 * 2048 + (laneF ^ 64)); \
    } } while (0)
#define RDB(BUFB, NH, DST) do { \
    _Pragma("unroll") for (int n2 = 0; n2 < 2; ++n2) { \
        DST[n2][0] = *(const bf16x8*)(lds + (BUFB) * 65536 + bWave + (NH) * 4096 + n2 * 2048 + laneF); \
        DST[n2][1] = *(const bf16x8*)(lds + (BUFB) * 65536 + bWave + (NH) * 4096 + n2 * 2048 + (laneF ^ 64)); \
    } } while (0)

// one C-quadrant x K=64: 16 MFMA (8 indep chains per kstep)
#define MM16(AA, BB, MH, NH) do { \
    __builtin_amdgcn_s_setprio(1); \
    _Pragma("unroll") for (int ks = 0; ks < 2; ++ks) \
    _Pragma("unroll") for (int n2 = 0; n2 < 2; ++n2) \
    _Pragma("unroll") for (int m2 = 0; m2 < 4; ++m2) \
        acc[(MH) * 4 + m2][(NH) * 2 + n2] = __builtin_amdgcn_mfma_f32_16x16x32_bf16( \
            AA[m2][ks], BB[n2][ks], acc[(MH) * 4 + m2][(NH) * 2 + n2], 0, 0, 0); \
    __builtin_amdgcn_s_setprio(0); \
} while (0)

template <int MODE>
__global__ __launch_bounds__(512, 2) void k_gemm8p(
    const u16* __restrict__ A, const u16* __restrict__ B,
    const u16* __restrict__ bias, void* __restrict__ Cv,
    int K, int ldc, int mReal, int nReal, int gx, int nTiles) {
    __shared__ __align__(16) char lds[131072];

    const int tid  = threadIdx.x;
    const int w    = tid >> 6, lane = tid & 63;
    const int wc   = w & 3, wr = w >> 2;            // 2M x 4N waves, per-wave 128x64
    const int l15  = lane & 15, lg4 = lane >> 4;

    // bijective XCD-chunked swizzle (m204 form)
    const int nwg = (int)gridDim.x;
    const int q   = nwg >> 3, r = nwg & 7;
    const int xcd = (int)blockIdx.x & 7, lid = (int)blockIdx.x >> 3;
    const int wg0 = (xcd < r ? xcd * (q + 1) : r * (q + 1) + (xcd - r) * q) + lid;

    // frag-read lane offset: row = l&15, chunk slot = ((l>>4) ^ (l&7)); ^64 => +4 chunks (kstep1)
    const int laneF = l15 * 128 + (((lane >> 4) ^ (lane & 7)) << 4);
    const int aWave = wr * 16384;                                   // A-half = wr
    const int bWave = 32768 + (wc >> 1) * 16384 + (wc & 1) * 8192;  // B-half = wc>>1

    // staging geometry: lane covers (row = w*8 + lane>>3 [+64/sweep], chunk cOrig)
    const int cOrig = (lane & 7) ^ ((lane >> 3) & 7);
    const int sRow  = w * 8 + (lane >> 3);
    const int ldsW  = w * 1024;                      // wave-uniform LDS slot

    const int nIt = K >> 7;                          // iterations of 2 K-tiles

    for (int v = wg0; v < nTiles; v += (int)gridDim.x) {
        const int bm = (v / gx) * 256;
        const int bn = (v % gx) * 256;
        const u16* const aStage = A + (size_t)(bm + sRow) * K + cOrig * 8;
        const u16* const bStage = B + (size_t)(bn + sRow) * K + cOrig * 8;

        f32x4 acc[8][4];
#pragma unroll
        for (int i = 0; i < 8; ++i)
#pragma unroll
            for (int j = 0; j < 4; ++j) acc[i][j] = (f32x4)(0.f);

        bf16x8 a[4][2], b0[2][2], b1[2][2];

        // prologue: buf0 full (T0, 8 loads) + buf1.B (T1, 4 loads); VMCNT(4) => T0 landed
        STG_A(0, 0, 0);  STG_B(0, 0, 0);  STG_A(0, 1, 0);  STG_B(0, 1, 0);
        STG_B(1, 0, 64); STG_B(1, 1, 64);
        VMCNT(4);
        BARRIER();

#pragma unroll 1
        for (int it = 0; it < nIt; ++it) {
            const bool ok = (it + 1 < nIt);
            const size_t kT1 = (size_t)(2 * it + 1) * 64;
            const size_t kS  = (size_t)(2 * it + 2) * 64;
            // ph1: Q00 of tile 2it (buf0); stage buf1.A0 <- 2it+1 (free since prev ph8)
            RDA(0, 0); RDB(0, 0, b0); STG_A(1, 0, kT1);
            LGKM8(); BARRIER(); LGKM0(); MM16(a, b0, 0, 0); BARRIER();
            // ph2: Q01; stage buf1.A1 <- 2it+1
            RDB(0, 1, b1); STG_A(1, 1, kT1);
            BARRIER(); LGKM0(); MM16(a, b1, 0, 1); BARRIER();
            // ph3: Q11; stage buf0.B0 <- 2it+2 (buf0.B free: reads done ph1+ph2)
            RDA(0, 1); if (ok) { STG_B(0, 0, kS); }
            BARRIER(); LGKM0(); MM16(a, b1, 1, 1); BARRIER();
            // ph4: Q10 (0 reads); stage buf0.B1; VMCNT(4) => buf1 complete before ph5
            if (ok) { STG_B(0, 1, kS); VMCNT(4); } else { VMCNT(0); }
            BARRIER(); MM16(a, b0, 1, 0); BARRIER();
            // ph5: Q00 of tile 2it+1 (buf1); stage buf0.A0 <- 2it+2 (buf0.A free at ph4)
            RDA(1, 0); RDB(1, 0, b0); if (ok) { STG_A(0, 0, kS); }
            LGKM8(); BARRIER(); LGKM0(); MM16(a, b0, 0, 0); BARRIER();
            // ph6: Q01; stage buf0.A1
            RDB(1, 1, b1); if (ok) { STG_A(0, 1, kS); }
            BARRIER(); LGKM0(); MM16(a, b1, 0, 1); BARRIER();
            // ph7: Q11; stage buf1.B0 <- 2it+3 (buf1.B free: reads done ph5+ph6)
            RDA(1, 1); if (ok) { STG_B(1, 0, kS + 64); }
            BARRIER(); LGKM0(); MM16(a, b1, 1, 1); BARRIER();
            // ph8: Q10 (0 reads); stage buf1.B1; VMCNT(4) => buf0 complete before next ph1
            if (ok) { STG_B(1, 1, kS + 64); VMCNT(4); }
            BARRIER(); MM16(a, b0, 1, 0); BARRIER();
        }

        // epilogue. 16x16 C/D layout (m89/m91): col = lane&15, row = (lane>>4)*4 + reg
        float bv[4];
        if (MODE >= 1) {
#pragma unroll
            for (int ni = 0; ni < 4; ++ni) bv[ni] = b2f(bias[bn + wc * 64 + ni * 16 + l15]);
        }
#pragma unroll
        for (int mi = 0; mi < 8; ++mi) {
#pragma unroll
            for (int ni = 0; ni < 4; ++ni) {
#pragma unroll
                for (int rg = 0; rg < 4; ++rg) {
                    const int row = bm + wr * 128 + mi * 16 + lg4 * 4 + rg;
                    const int col = bn + wc * 64 + ni * 16 + l15;
                    float vv = acc[mi][ni][rg];
                    if (MODE == 0) {
                        if (row < mReal && col < nReal)
                            ((u16*)Cv)[(size_t)row * ldc + col] = f2bf(vv);
                    } else if (MODE == 1) {
                        vv += bv[ni];
                        vv = vv > 0.f ? vv : 0.f;
                        ((u16*)Cv)[(size_t)row * ldc + col] = f2bf(vv);
                    } else {
                        ((float*)Cv)[(size_t)row * ldc + col] = vv + bv[ni];
                    }
                }
            }
        }
    }
}

// ---------- launch ----------
// Sizes: D_IN=2048, D_H=4096, D_OUT=2048, B=4096; SIZE_N=5794, SIZE_M=2897
// Padded GEMM0 dims: M=N=5888 (23*256), K=2944 (23*128)
// Vf flat unpack offsets (elems):
//   W1 @ 0, b1 @ 8388608, W2 @ 8392704, b2 @ 25169920, W3 @ 25174016, b3 @ 33562624
extern "C" void kernel_launch(void* const* d_in, const int* in_sizes, int n_in,
                              void* d_out, int out_size, void* d_ws, size_t ws_size,
                              hipStream_t stream) {
    (void)in_sizes; (void)n_in; (void)out_size; (void)ws_size;
    const float* x  = (const float*)d_in[0];
    const float* V1 = (const float*)d_in[1];
    const float* V2 = (const float*)d_in[2];

    char* ws = (char*)d_ws;
    u16* Vf   = (u16*)(ws);                            // 5794*5794 bf16 -> 67,140,872 B
    u16* V1b  = (u16*)(ws + 67141120);                 // [5888 x 2944] bf16 = 34,668,544 B
    u16* V2bT = (u16*)(ws + 67141120 + 34668544);      // [5888 x 2944] bf16
    u16* Xb   = (u16*)(ws + 67141120 + 2 * 34668544);  // [4096 x 2048] bf16
    u16* H1   = V1b;   // dead after GEMM0
    u16* H2   = V2bT;

    k_conv_pad<<<8464, 256, 0, stream>>>(V1, V1b, 5794, 2897, 2944, 5888 * 2944 / 8);
    k_transpose_conv<<<dim3(92, 184), dim3(32, 8), 0, stream>>>(V2, V2bT, 2897, 5794, 2944);
    k_conv_pad<<<4096, 256, 0, stream>>>(x, Xb, 4096, 2048, 2048, 4096 * 2048 / 8);

    // G0: Vf = V1 @ V2  (padded 5888x5888x2944; 529 tiles persistent over 512 blocks)
    k_gemm8p<0><<<512, 512, 0, stream>>>(V1b, V2bT, nullptr, Vf,
                                         2944, 5794, 5794, 5794, 23, 529);
    // G1: H1 = relu(Xb @ W1^T + b1)   [4096x4096], K=2048 (16x16 = 256 tiles, 1 round)
    k_gemm8p<1><<<256, 512, 0, stream>>>(Xb, Vf + 0, Vf + 8388608, H1,
                                         2048, 4096, 4096, 4096, 16, 256);
    // G2: H2 = relu(H1 @ W2^T + b2)   [4096x4096], K=4096
    k_gemm8p<1><<<256, 512, 0, stream>>>(H1, Vf + 8392704, Vf + 25169920, H2,
                                         4096, 4096, 4096, 4096, 16, 256);
    // G3: out = H2 @ W3^T + b3        [4096x2048] fp32, K=4096 (old 128^2 kernel)
    k_gemm_bt<2><<<dim3(16, 32), 256, 0, stream>>>(H2, Vf + 25174016, Vf + 33562624, d_out,
                                                   4096, 2048, 4096, 2048);
}